// Round 8
// baseline (246.261 us; speedup 1.0000x reference)
//
#include <hip/hip_runtime.h>

// VQ-VAE forward + EMA update, MI355X — 2 kernels (prep + main-with-finalize).
// Sizes fixed by the reference: B=64, C=D=8, H=W=64, K=512.
constexpr int Kc   = 512;
constexpr int Dc   = 8;
constexpr int HWc  = 4096;            // 64*64
constexpr int CHWc = Dc * HWc;        // 32768
constexpr int Mc   = 64 * HWc;        // 262144 vectors
constexpr int TOTALc = Mc * Dc;       // 2097152 elements of z / z_q

// 8 replica accumulators to spread atomic traffic; device-scope fp atomics
// proven cross-XCD coherent in R1-R6.
constexpr int REP      = 8;
constexpr int RSTRIDE  = 4616;        // 512 counts + 4096 sums + 1 loss + 7 pad
constexpr int ACC_FLOATS = REP * RSTRIDE;   // 36928 floats (~148 KB)
// d_ws float layout:
//   [0 .. ACC_FLOATS)        replica accumulators (counts | sums | loss | pad) x8
//   [ACC_FLOATS .. +512)     e_sq[k]
//   [ACC_FLOATS+512]         done-counter (uint32)

__global__ __launch_bounds__(256) void vq_prep(const float* __restrict__ cb,
                                               float* __restrict__ ws) {
    const int tid = blockIdx.x * 256 + threadIdx.x;
    float4* w4 = (float4*)ws;
    for (int i = tid; i < ACC_FLOATS / 4; i += gridDim.x * 256)
        w4[i] = float4{0.f, 0.f, 0.f, 0.f};
    if (blockIdx.x == 0) {
        for (int k = threadIdx.x; k < Kc; k += 256) {
            float s = 0.f;
#pragma unroll
            for (int c = 0; c < Dc; ++c) {
                const float e = cb[k * Dc + c];
                s = fmaf(e, e, s);
            }
            ws[ACC_FLOATS + k] = s;
        }
        if (threadIdx.x == 0)
            ((unsigned*)ws)[ACC_FLOATS + 512] = 0u;   // done-counter
    }
}

// 1024 blocks x 512 threads; block owns 256 consecutive vectors.
// k-group g = t>>7 (2 waves) scans codes [g*128, g*128+128); each thread
// scores V=2 vectors (vl, vl+128). The LAST block to finish its flush also
// performs the EMA finalize (saves a third kernel dispatch).
__global__ __launch_bounds__(512, 8) void vq_main(const float* __restrict__ z,
                                                  const float* __restrict__ cb,
                                                  const float* __restrict__ esq,
                                                  const float* __restrict__ ema_cs,
                                                  const float* __restrict__ ema_w,
                                                  float* __restrict__ ws,
                                                  float* __restrict__ out) {
    __shared__ __align__(16) float s_counts[Kc];
    __shared__ __align__(16) float s_sums[Kc * Dc];
    __shared__ float s_mn[4][256];
    __shared__ int   s_im[4][256];
    __shared__ float s_loss;
    __shared__ int   s_last;

    const int t = threadIdx.x;
    {   // vectorized LDS zeroing
        const float4 z4 = {0.f, 0.f, 0.f, 0.f};
        float4* sc4 = (float4*)s_counts;          // 128 entries
        float4* ss4 = (float4*)s_sums;            // 1024 entries
        if (t < 128) sc4[t] = z4;
        for (int i = t; i < Kc * Dc / 4; i += 512) ss4[i] = z4;
        if (t == 0) s_loss = 0.f;
    }

    const int vl = t & 127;
    // wave-uniform k-group; readfirstlane keeps codebook indices provably
    // uniform -> s_load (scalar) path for cb/esq.
    const int g  = __builtin_amdgcn_readfirstlane(t >> 7);   // 0..3
    const int k0 = g << 7;

    const int base = blockIdx.x * 256;        // 256-aligned -> one batch idx
    const int n0 = (base + vl) & (HWc - 1);
    const int b  = base >> 12;
    const float* zb = z + b * CHWc + n0;

    float zz0[Dc], zz1[Dc];
#pragma unroll
    for (int c = 0; c < Dc; ++c) {
        zz0[c] = -2.0f * zb[c * HWc];         // coalesced across lanes
        zz1[c] = -2.0f * zb[c * HWc + 128];
    }

    // argmin over this k-group: score = e_sq[k] - 2*dot(z,e_k) (monotone-eq).
    float mn0 = 3.4e38f, mn1 = 3.4e38f;
    int   i0 = k0, i1 = k0;
#pragma unroll 4
    for (int kk = 0; kk < 128; ++kk) {
        const int k = k0 + kk;
        float a0 = esq[k];                    // uniform -> s_load
        float a1 = a0;
#pragma unroll
        for (int c = 0; c < Dc; ++c) {
            const float e = cb[k * Dc + c];   // uniform -> s_load
            a0 = fmaf(zz0[c], e, a0);
            a1 = fmaf(zz1[c], e, a1);
        }
        const bool c0 = a0 < mn0;  // strict <: first index wins ties (ref)
        mn0 = c0 ? a0 : mn0;
        i0  = c0 ? k  : i0;
        const bool c1 = a1 < mn1;
        mn1 = c1 ? a1 : mn1;
        i1  = c1 ? k  : i1;
    }
    s_mn[g][vl]       = mn0;
    s_im[g][vl]       = i0;
    s_mn[g][vl + 128] = mn1;
    s_im[g][vl + 128] = i1;
    __syncthreads();

    if (t < 256) {
        const int v = t;                      // block-local vector id
        float mnv = s_mn[0][v];
        int   imv = s_im[0][v];
#pragma unroll
        for (int gg = 1; gg < 4; ++gg) {
            const float m2 = s_mn[gg][v];     // groups ascending in k:
            const int   j2 = s_im[gg][v];     // strict < keeps first index
            const bool  c2 = m2 < mnv;
            mnv = c2 ? m2 : mnv;
            imv = c2 ? j2 : imv;
        }

        // Recover this thread's merge-vector z from registers (exact pow2):
        // t<128 -> vector vl (zz0), t>=128 -> vector vl+128 (zz1).
        float zr[Dc];
#pragma unroll
        for (int c = 0; c < Dc; ++c)
            zr[c] = -0.5f * ((t < 128) ? zz0[c] : zz1[c]);

        // Gather old-codebook row (16 KB table, L1-hot; 32B/lane).
        const float4* cb4 = (const float4*)cb;
        const float4 qa = cb4[imv * 2], qb = cb4[imv * 2 + 1];
        const float q[Dc] = {qa.x, qa.y, qa.z, qa.w, qb.x, qb.y, qb.z, qb.w};

        const int nv = (base + v) & (HWc - 1);
        float* zqv = out + b * CHWc + nv;     // z_q output
        float lsum = 0.f;
#pragma unroll
        for (int c = 0; c < Dc; ++c) {
            zqv[c * HWc] = q[c];              // coalesced stores
            const float d = q[c] - zr[c];
            lsum = fmaf(d, d, lsum);
        }

        // Per-block LDS histogram (ds_add_f32).
        unsafeAtomicAdd(&s_counts[imv], 1.0f);
#pragma unroll
        for (int c = 0; c < Dc; ++c)
            unsafeAtomicAdd(&s_sums[imv * Dc + c], zr[c]);
        unsafeAtomicAdd(&s_loss, lsum);
    }
    __syncthreads();

    // Flush non-zero bins to this block's replica accumulator (all 512 thr).
    {
        float* acc = ws + (blockIdx.x & (REP - 1)) * RSTRIDE;
        for (int i = t; i < Kc; i += 512) {
            const float val = s_counts[i];
            if (val != 0.f) unsafeAtomicAdd(&acc[i], val);
        }
        for (int i = t; i < Kc * Dc; i += 512) {
            const float val = s_sums[i];
            if (val != 0.f) unsafeAtomicAdd(&acc[512 + i], val);
        }
        if (t == 0) unsafeAtomicAdd(&acc[4608], s_loss);
    }

    // ---- last-block handshake: all flush atomics globally performed, then
    // exactly one block runs the EMA finalize. ----
    __threadfence();                          // order flush before counter
    __syncthreads();
    if (t == 0) {
        unsigned* ctr = (unsigned*)(ws + ACC_FLOATS + 512);
        const unsigned old = __hip_atomic_fetch_add(ctr, 1u, __ATOMIC_ACQ_REL,
                                                    __HIP_MEMORY_SCOPE_AGENT);
        s_last = (old == gridDim.x - 1) ? 1 : 0;
    }
    __syncthreads();
    if (s_last == 0) return;
    __threadfence();                          // acquire for all threads

    // ================= EMA finalize (one block, 512 threads) ===============
    constexpr float DEC  = 0.99f;
    constexpr float OMD  = (float)(1.0 - 0.99);      // matches jnp f32 cast
    constexpr float EPSf = 1e-5f;
    constexpr float KEPS = (float)(512 * 1e-5);      // 0.00512
    float* s_ncs = &s_mn[0][0];                      // reuse dead LDS (512 f)

    float cnt = 0.f;
#pragma unroll
    for (int r = 0; r < REP; ++r)
        cnt += __hip_atomic_load(&ws[r * RSTRIDE + t], __ATOMIC_RELAXED,
                                 __HIP_MEMORY_SCOPE_AGENT);
    const float ncs = ema_cs[t] * DEC + cnt * OMD;
    s_ncs[t]    = ncs;
    s_counts[t] = ncs;                               // reduction buffer
    __syncthreads();
    for (int s = 256; s > 0; s >>= 1) {
        if (t < s) s_counts[t] += s_counts[t + s];
        __syncthreads();
    }
    const float n = s_counts[0];

    float* out_loss = out + TOTALc;          // [1]
    float* out_cb   = out + TOTALc + 1;      // [K*D]
    float* out_cs   = out_cb + Kc * Dc;      // [K]
    float* out_nw   = out_cs + Kc;           // [K*D]

    out_cs[t] = (ncs + EPSf) / (n + KEPS) * n;

    for (int e = t; e < Kc * Dc; e += 512) {
        const float ncs_k = s_ncs[e >> 3];
        const float cs_k  = (ncs_k + EPSf) / (n + KEPS) * n;
        float sm = 0.f;
#pragma unroll
        for (int r = 0; r < REP; ++r)
            sm += __hip_atomic_load(&ws[r * RSTRIDE + 512 + e],
                                    __ATOMIC_RELAXED,
                                    __HIP_MEMORY_SCOPE_AGENT);
        const float nw = ema_w[e] * DEC + sm * OMD;
        out_nw[e] = nw;
        out_cb[e] = nw / cs_k;
    }
    if (t == 0) {
        float ls = 0.f;
#pragma unroll
        for (int r = 0; r < REP; ++r)
            ls += __hip_atomic_load(&ws[r * RSTRIDE + 4608], __ATOMIC_RELAXED,
                                    __HIP_MEMORY_SCOPE_AGENT);
        out_loss[0] = ls * (1.0f / 2097152.0f);      // /2^21 exact
    }
}

extern "C" void kernel_launch(void* const* d_in, const int* in_sizes, int n_in,
                              void* d_out, int out_size, void* d_ws, size_t ws_size,
                              hipStream_t stream) {
    const float* z      = (const float*)d_in[0];
    const float* cb     = (const float*)d_in[1];
    const float* ema_cs = (const float*)d_in[2];
    const float* ema_w  = (const float*)d_in[3];
    float* out = (float*)d_out;
    float* ws  = (float*)d_ws;

    vq_prep<<<32, 256, 0, stream>>>(cb, ws);
    vq_main<<<Mc / 256, 512, 0, stream>>>(z, cb, ws + ACC_FLOATS,
                                          ema_cs, ema_w, ws, out);
}

// Round 9
// 145.551 us; speedup vs baseline: 1.6919x; 1.6919x over previous
//
#include <hip/hip_runtime.h>

// VQ-VAE forward + EMA update, MI355X.
// Sizes fixed by the reference: B=64, C=D=8, H=W=64, K=512.
constexpr int Kc   = 512;
constexpr int Dc   = 8;
constexpr int HWc  = 4096;            // 64*64
constexpr int CHWc = Dc * HWc;        // 32768
constexpr int Mc   = 64 * HWc;        // 262144 vectors
constexpr int TOTALc = Mc * Dc;       // 2097152 elements of z / z_q

constexpr int REP = 8;                // replica accumulators for atomics

// ---- Path A (direct): ws layout (floats) ----
//   [0 .. 8*520)      counts replicas (512 counts | 1 loss | 7 pad), stride 520
//   [4160 .. 4672)    e_sq[k]
//   [8192 .. +512*4096) per-block sums partials, row b = ws[8192 + b*4096 ..]
constexpr int RSTR_A   = 520;
constexpr int ESQ_A    = 4160;
constexpr int SUMS_OFF = 8192;
constexpr size_t NEED_A = (size_t)(SUMS_OFF + 512 * 4096) * 4;   // 8.42 MB

// ---- Path B (atomic fallback): R4 layout ----
constexpr int RSTR_B     = 4616;      // 512 counts + 4096 sums + 1 loss + 7 pad
constexpr int ACC_B      = REP * RSTR_B;    // 36928 floats
constexpr int ESQ_B      = ACC_B;

__global__ __launch_bounds__(256) void vq_prep(const float* __restrict__ cb,
                                               float* __restrict__ ws,
                                               int nzero4, int esq_off) {
    const int tid = blockIdx.x * 256 + threadIdx.x;
    float4* w4 = (float4*)ws;
    for (int i = tid; i < nzero4; i += gridDim.x * 256)
        w4[i] = float4{0.f, 0.f, 0.f, 0.f};
    if (blockIdx.x == 0) {
        for (int k = threadIdx.x; k < Kc; k += 256) {
            float s = 0.f;
#pragma unroll
            for (int c = 0; c < Dc; ++c) {
                const float e = cb[k * Dc + c];
                s = fmaf(e, e, s);
            }
            ws[esq_off + k] = s;
        }
    }
}

// 512 blocks x 1024 threads; block owns 512 consecutive vectors.
// k-group g = t>>8 (4 waves) scans codes [g*128, g*128+128); each thread
// scores V=2 vectors (vl, vl+256). 2 blocks/CU * 16 waves = 32 waves/CU.
// DIRECT: sums flushed as plain coalesced stores to a per-block partial row
// (no atomics); counts/loss stay atomic (cheap). !DIRECT: R4 atomic flush.
template <bool DIRECT>
__global__ __launch_bounds__(1024, 8) void vq_main(const float* __restrict__ z,
                                                   const float* __restrict__ cb,
                                                   const float* __restrict__ esq,
                                                   float* __restrict__ ws,
                                                   float* __restrict__ out) {
    __shared__ __align__(16) float s_counts[Kc];
    __shared__ __align__(16) float s_sums[Kc * Dc];
    __shared__ float s_mn[4][512];
    __shared__ int   s_im[4][512];
    __shared__ float s_loss;

    const int t = threadIdx.x;
    {   // vectorized LDS zeroing (1024 threads)
        const float4 z4 = {0.f, 0.f, 0.f, 0.f};
        float4* sc4 = (float4*)s_counts;          // 128 entries
        float4* ss4 = (float4*)s_sums;            // 1024 entries
        if (t < 128) sc4[t] = z4;
        ss4[t] = z4;
        if (t == 0) s_loss = 0.f;
    }

    const int vl = t & 255;
    // wave-uniform k-group; readfirstlane keeps codebook indices provably
    // uniform -> s_load (scalar) path for cb/esq.
    const int g  = __builtin_amdgcn_readfirstlane(t >> 8);   // 0..3
    const int k0 = g << 7;

    const int base = blockIdx.x * 512;        // 512-aligned -> one batch idx
    const int n0 = (base + vl) & (HWc - 1);
    const int b  = base >> 12;
    const float* zb = z + b * CHWc + n0;

    float zz0[Dc], zz1[Dc];
#pragma unroll
    for (int c = 0; c < Dc; ++c) {
        zz0[c] = -2.0f * zb[c * HWc];         // coalesced across lanes
        zz1[c] = -2.0f * zb[c * HWc + 256];
    }

    // argmin over this k-group: score = e_sq[k] - 2*dot(z,e_k) (monotone-eq).
    float mn0 = 3.4e38f, mn1 = 3.4e38f;
    int   i0 = k0, i1 = k0;
#pragma unroll 4
    for (int kk = 0; kk < 128; ++kk) {
        const int k = k0 + kk;
        float a0 = esq[k];                    // uniform -> s_load
        float a1 = a0;
#pragma unroll
        for (int c = 0; c < Dc; ++c) {
            const float e = cb[k * Dc + c];   // uniform -> s_load
            a0 = fmaf(zz0[c], e, a0);
            a1 = fmaf(zz1[c], e, a1);
        }
        const bool c0 = a0 < mn0;  // strict <: first index wins ties (ref)
        mn0 = c0 ? a0 : mn0;
        i0  = c0 ? k  : i0;
        const bool c1 = a1 < mn1;
        mn1 = c1 ? a1 : mn1;
        i1  = c1 ? k  : i1;
    }
    s_mn[g][vl]       = mn0;
    s_im[g][vl]       = i0;
    s_mn[g][vl + 256] = mn1;
    s_im[g][vl + 256] = i1;
    __syncthreads();

    if (t < 512) {
        const int v = t;                      // block-local vector id
        float mnv = s_mn[0][v];
        int   imv = s_im[0][v];
#pragma unroll
        for (int gg = 1; gg < 4; ++gg) {
            const float m2 = s_mn[gg][v];     // groups ascending in k:
            const int   j2 = s_im[gg][v];     // strict < keeps first index
            const bool  c2 = m2 < mnv;
            mnv = c2 ? m2 : mnv;
            imv = c2 ? j2 : imv;
        }

        // Recover merge-vector z from registers (exact pow2):
        // t<256 -> vector vl (zz0), t>=256 -> vector vl+256 (zz1).
        float zr[Dc];
#pragma unroll
        for (int c = 0; c < Dc; ++c)
            zr[c] = -0.5f * ((t < 256) ? zz0[c] : zz1[c]);

        // Gather old-codebook row (16 KB table, L1-hot; 32B/lane).
        const float4* cb4 = (const float4*)cb;
        const float4 qa = cb4[imv * 2], qb = cb4[imv * 2 + 1];
        const float q[Dc] = {qa.x, qa.y, qa.z, qa.w, qb.x, qb.y, qb.z, qb.w};

        const int nv = (base + v) & (HWc - 1);
        float* zqv = out + b * CHWc + nv;     // z_q output
        float lsum = 0.f;
#pragma unroll
        for (int c = 0; c < Dc; ++c) {
            zqv[c * HWc] = q[c];              // coalesced stores
            const float d = q[c] - zr[c];
            lsum = fmaf(d, d, lsum);
        }

        // Per-block LDS histogram (ds_add_f32).
        unsafeAtomicAdd(&s_counts[imv], 1.0f);
#pragma unroll
        for (int c = 0; c < Dc; ++c)
            unsafeAtomicAdd(&s_sums[imv * Dc + c], zr[c]);
        unsafeAtomicAdd(&s_loss, lsum);
    }
    __syncthreads();

    // ---- flush ----
    if (DIRECT) {
        float* acc = ws + (blockIdx.x & (REP - 1)) * RSTR_A;
        if (t < Kc) {
            const float val = s_counts[t];
            if (val != 0.f) unsafeAtomicAdd(&acc[t], val);
        }
        // sums: plain coalesced per-block partial row (no atomics)
        float4* dst = (float4*)(ws + SUMS_OFF + blockIdx.x * (Kc * Dc));
        dst[t] = ((float4*)s_sums)[t];        // 1024 float4 = 4096 floats
        if (t == 0) unsafeAtomicAdd(&acc[Kc], s_loss);
    } else {
        float* acc = ws + (blockIdx.x & (REP - 1)) * RSTR_B;
        if (t < Kc) {
            const float val = s_counts[t];
            if (val != 0.f) unsafeAtomicAdd(&acc[t], val);
        }
        for (int i = t; i < Kc * Dc; i += 1024) {
            const float val = s_sums[i];
            if (val != 0.f) unsafeAtomicAdd(&acc[512 + i], val);
        }
        if (t == 0) unsafeAtomicAdd(&acc[4608], s_loss);
    }
}

// ---- Path A finalize: 33 blocks x 512. Blocks 0..31 reduce 128 elements
// each over 512 partial rows (coalesced over e); block 32 writes cs + loss.
__global__ __launch_bounds__(512) void vq_final_direct(const float* __restrict__ ws,
                                                       const float* __restrict__ ema_cs,
                                                       const float* __restrict__ ema_w,
                                                       float* __restrict__ out) {
    constexpr float DEC  = 0.99f;
    constexpr float OMD  = (float)(1.0 - 0.99);      // matches jnp f32 cast
    constexpr float EPSf = 1e-5f;
    constexpr float KEPS = (float)(512 * 1e-5);      // 0.00512
    __shared__ float s_ncs[Kc];
    __shared__ float s_red[Kc];
    __shared__ float s_part[Kc];

    const int t   = threadIdx.x;
    const int blk = blockIdx.x;

    // every block: ncs[k] + n (redundant, deterministic, identical)
    float cnt = 0.f;
#pragma unroll
    for (int r = 0; r < REP; ++r) cnt += ws[r * RSTR_A + t];
    const float ncs = ema_cs[t] * DEC + cnt * OMD;
    s_ncs[t] = ncs;
    s_red[t] = ncs;
    __syncthreads();
    for (int s = 256; s > 0; s >>= 1) {
        if (t < s) s_red[t] += s_red[t + s];
        __syncthreads();
    }
    const float n = s_red[0];

    float* out_loss = out + TOTALc;          // [1]
    float* out_cb   = out + TOTALc + 1;      // [K*D]
    float* out_cs   = out_cb + Kc * Dc;      // [K]
    float* out_nw   = out_cs + Kc;           // [K*D]

    if (blk == 32) {
        out_cs[t] = (ncs + EPSf) / (n + KEPS) * n;
        if (t == 0) {
            float ls = 0.f;
#pragma unroll
            for (int r = 0; r < REP; ++r) ls += ws[r * RSTR_A + Kc];
            out_loss[0] = ls * (1.0f / 2097152.0f);  // /2^21 exact
        }
        return;
    }

    // blocks 0..31: elements e in [blk*128, blk*128+128), 4-way r-split
    const int el = t & 127;
    const int rg = t >> 7;                   // 0..3
    const int e  = blk * 128 + el;
    float sm = 0.f;
    for (int r = rg; r < 512; r += 4)        // lanes coalesced over e
        sm += ws[SUMS_OFF + r * (Kc * Dc) + e];
    s_part[t] = sm;
    __syncthreads();
    if (t < 128) {
        const float smf = s_part[t] + s_part[t + 128] +
                          s_part[t + 256] + s_part[t + 384];
        const int e0 = blk * 128 + t;
        const float ncs_k = s_ncs[e0 >> 3];
        const float cs_k  = (ncs_k + EPSf) / (n + KEPS) * n;
        const float nw = ema_w[e0] * DEC + smf * OMD;
        out_nw[e0] = nw;
        out_cb[e0] = nw / cs_k;
    }
}

// ---- Path B finalize: R4's single-block version (atomic replicas). ----
__global__ __launch_bounds__(512) void vq_final_atomic(const float* __restrict__ ws,
                                                       const float* __restrict__ ema_cs,
                                                       const float* __restrict__ ema_w,
                                                       float* __restrict__ out) {
    constexpr float DEC  = 0.99f;
    constexpr float OMD  = (float)(1.0 - 0.99);
    constexpr float EPSf = 1e-5f;
    constexpr float KEPS = (float)(512 * 1e-5);
    __shared__ float red[512];
    __shared__ float s_cs[512];

    const int t = threadIdx.x;
    float cnt = 0.f;
#pragma unroll
    for (int r = 0; r < REP; ++r) cnt += ws[r * RSTR_B + t];
    const float ncs = ema_cs[t] * DEC + cnt * OMD;
    red[t] = ncs;
    __syncthreads();
    for (int s = 256; s > 0; s >>= 1) {
        if (t < s) red[t] += red[t + s];
        __syncthreads();
    }
    const float n  = red[0];
    const float cs = (ncs + EPSf) / (n + KEPS) * n;
    s_cs[t] = cs;

    float* out_loss = out + TOTALc;
    float* out_cb   = out + TOTALc + 1;
    float* out_cs   = out_cb + Kc * Dc;
    float* out_nw   = out_cs + Kc;

    out_cs[t] = cs;
    __syncthreads();

    for (int e = t; e < Kc * Dc; e += 512) {
        float sm = 0.f;
#pragma unroll
        for (int r = 0; r < REP; ++r) sm += ws[r * RSTR_B + 512 + e];
        const float nw = ema_w[e] * DEC + sm * OMD;
        out_nw[e] = nw;
        out_cb[e] = nw / s_cs[e >> 3];
    }
    if (t == 0) {
        float ls = 0.f;
#pragma unroll
        for (int r = 0; r < REP; ++r) ls += ws[r * RSTR_B + 4608];
        out_loss[0] = ls * (1.0f / 2097152.0f);
    }
}

extern "C" void kernel_launch(void* const* d_in, const int* in_sizes, int n_in,
                              void* d_out, int out_size, void* d_ws, size_t ws_size,
                              hipStream_t stream) {
    const float* z      = (const float*)d_in[0];
    const float* cb     = (const float*)d_in[1];
    const float* ema_cs = (const float*)d_in[2];
    const float* ema_w  = (const float*)d_in[3];
    float* out = (float*)d_out;
    float* ws  = (float*)d_ws;

    if (ws_size >= NEED_A) {   // ws_size is fixed per process -> graph-safe
        vq_prep<<<32, 256, 0, stream>>>(cb, ws, (REP * RSTR_A) / 4, ESQ_A);
        vq_main<true><<<Mc / 512, 1024, 0, stream>>>(z, cb, ws + ESQ_A, ws, out);
        vq_final_direct<<<33, 512, 0, stream>>>(ws, ema_cs, ema_w, out);
    } else {
        vq_prep<<<32, 256, 0, stream>>>(cb, ws, (ACC_B + 3) / 4, ESQ_B);
        vq_main<false><<<Mc / 512, 1024, 0, stream>>>(z, cb, ws + ESQ_B, ws, out);
        vq_final_atomic<<<1, 512, 0, stream>>>(ws, ema_cs, ema_w, out);
    }
}